// Round 1
// 332.769 us; speedup vs baseline: 1.0867x; 1.0867x over previous
//
#include <hip/hip_runtime.h>

// ---------------------------------------------------------------------------
// HolographicMemory: out = softmax( x @ [Kr|Ki]^T * temp ) @ [Vr|Vi]
//   x: [32768, 1024] fp32, MEM=512, HEAD=512.
// v2: fuse pack_x + energy-GEMM + softmax into one kernel.
//   - block = 64 rows x 512 cols (FULL softmax row), 4 waves, each 64x128
//   - x staged as fp32 via global_load_lds, cvt->bf16 at fragment read
//   - XOR-swizzled LDS (source-side + read-side, rule #21) to kill bank
//     conflicts that padding can't fix under global_load_lds
//   - softmax: per-wave partials via __shfl_xor, 2 KiB LDS cross-wave combine
// gemm2 (attn @ V'^T) unchanged m97 structure.
// ---------------------------------------------------------------------------

#define DIMX   1024
#define MEMN   512
#define NROWS  32768
#define TEMP   0.04419417382415922f  // 512^-0.5

typedef __bf16 bf16;
typedef __bf16 bf16x8 __attribute__((ext_vector_type(8)));
typedef float  f32x4  __attribute__((ext_vector_type(4)));

// async global->LDS, 16B per lane; LDS dest is wave-uniform base + lane*16
__device__ __forceinline__ void gload_lds16(const void* g, void* l) {
    __builtin_amdgcn_global_load_lds(
        (const __attribute__((address_space(1))) unsigned*)g,
        (__attribute__((address_space(3))) unsigned*)l,
        16, 0, 0);
}

// ------- pack K' = [Kr|Ki] as [512][1024]; V'^T as [1024][512] (bf16) ------
__global__ __launch_bounds__(256) void pack_kv_kernel(const float* __restrict__ kr,
                                                      const float* __restrict__ ki,
                                                      const float* __restrict__ vr,
                                                      const float* __restrict__ vi,
                                                      bf16* __restrict__ Kb,
                                                      bf16* __restrict__ VbT) {
    const int idx = blockIdx.x * 256 + threadIdx.x;   // 0 .. 512*1024-1
    {   // Kb[m][h'] : h'<512 -> Kr[m][h'], else Ki[m][h'-512]
        const int m = idx >> 10, h = idx & 1023;
        const float v = (h < 512) ? kr[m * 512 + h] : ki[m * 512 + (h - 512)];
        Kb[idx] = (bf16)v;
    }
    {   // VbT[h'][m] : h'<512 -> Vr[m][h'], else Vi[m][h'-512]
        const int hp = idx >> 9, m = idx & 511;
        const float v = (hp < 512) ? vr[m * 512 + hp] : vi[m * 512 + (hp - 512)];
        VbT[idx] = (bf16)v;
    }
}

// ---------------------------------------------------------------------------
// Fused: energy = x @ Kb^T (bf16 MFMA), softmax over full row, write P bf16.
// Block: 64 rows x 512 cols, 256 threads (4 waves), wave wv owns cols
// wv*128..+127 of ALL 64 rows -> acc[4 row-tiles][8 col-tiles] f32x4.
// LDS: Xs [64][32] fp32 (8K, chunk^=(row&7) swizzle),
//      Ks [512][32] bf16 (32K, chunk^=((row>>1)&3) swizzle), red 2K.
// ---------------------------------------------------------------------------
__global__ __launch_bounds__(256, 2) void energy_softmax_kernel(
        const float* __restrict__ x,    // [32768][1024] fp32
        const bf16*  __restrict__ Kb,   // [512][1024]  bf16
        bf16* __restrict__ attn) {      // [32768][512] bf16 out
    __shared__ __align__(16) float Xs[64 * 32];
    __shared__ __align__(16) bf16  Ks[512 * 32];
    __shared__ float red[64][4][2];     // [row][wave][{max,sum}]

    const int tid  = threadIdx.x;
    const int wv   = tid >> 6, lane = tid & 63;
    const int lm   = lane & 15, g = lane >> 4;   // fragment coords
    const int rowB = blockIdx.x * 64;

    // staging coords (per-thread): X: 8 thr/row, 16B chunks; K: 4 thr/row
    const int xrow = tid >> 3, xchk = tid & 7;
    const int krow = tid >> 2, kchk = tid & 3;

    f32x4 acc[4][8] = {};

    for (int k0 = 0; k0 < DIMX; k0 += 32) {
        __syncthreads();   // prior iter's ds_reads done before overwrite
        // X: [64][32] fp32; source chunk pre-swizzled so LDS stays linear
        #pragma unroll
        for (int li = 0; li < 2; ++li) {
            const int r = li * 32 + xrow;
            gload_lds16(x + (size_t)(rowB + r) * DIMX + k0 + ((xchk ^ (r & 7)) << 2),
                        (char*)Xs + li * 4096 + wv * 1024);
        }
        // K: [512][32] bf16
        #pragma unroll
        for (int li = 0; li < 8; ++li) {
            const int r = li * 64 + krow;
            gload_lds16(Kb + (size_t)r * DIMX + k0 + ((kchk ^ ((r >> 1) & 3)) << 3),
                        (char*)Ks + li * 4096 + wv * 1024);
        }
        __syncthreads();   // emits s_waitcnt vmcnt(0) + barrier

        // A fragments: row = i*16+lm, k = g*8..+7 (fp32 chunks 2g,2g+1)
        bf16x8 af[4], bfr[8];
        #pragma unroll
        for (int i = 0; i < 4; ++i) {
            const int r = i * 16 + lm;
            const f32x4 lo = *(const f32x4*)((const char*)Xs + r * 128 + ((( 2*g )    ^ (r & 7)) << 4));
            const f32x4 hi = *(const f32x4*)((const char*)Xs + r * 128 + (((2*g + 1) ^ (r & 7)) << 4));
            bf16x8 a;
            a[0] = (bf16)lo[0]; a[1] = (bf16)lo[1]; a[2] = (bf16)lo[2]; a[3] = (bf16)lo[3];
            a[4] = (bf16)hi[0]; a[5] = (bf16)hi[1]; a[6] = (bf16)hi[2]; a[7] = (bf16)hi[3];
            af[i] = a;
        }
        // B fragments: K-row = wv*128 + j*16 + lm, k-chunk g
        #pragma unroll
        for (int j = 0; j < 8; ++j) {
            const int r = wv * 128 + j * 16 + lm;
            bfr[j] = *(const bf16x8*)((const char*)Ks + r * 64 + ((g ^ ((r >> 1) & 3)) << 4));
        }

        #pragma unroll
        for (int i = 0; i < 4; ++i)
            #pragma unroll
            for (int j = 0; j < 8; ++j)
                acc[i][j] = __builtin_amdgcn_mfma_f32_16x16x32_bf16(
                    af[i], bfr[j], acc[i][j], 0, 0, 0);
    }

    // ---- softmax epilogue --------------------------------------------------
    // C/D layout: col = j*16 + lm (+wv*128), row = i*16 + g*4 + reg.
    // Each (i,reg) is one row; its 8 j-values + 16-lane group = this wave's
    // 128-col slice. shfl_xor(1,2,4,8) stays inside the 16-lane group.
    float fac[4][4];
    #pragma unroll
    for (int i = 0; i < 4; ++i) {
        #pragma unroll
        for (int rg = 0; rg < 4; ++rg) {
            float m = acc[i][0][rg] * TEMP;
            #pragma unroll
            for (int j = 1; j < 8; ++j) m = fmaxf(m, acc[i][j][rg] * TEMP);
            m = fmaxf(m, __shfl_xor(m, 1));
            m = fmaxf(m, __shfl_xor(m, 2));
            m = fmaxf(m, __shfl_xor(m, 4));
            m = fmaxf(m, __shfl_xor(m, 8));
            float s = 0.f;
            #pragma unroll
            for (int j = 0; j < 8; ++j) {
                const float v = __expf(acc[i][j][rg] * TEMP - m);
                acc[i][j][rg] = v;  // keep exp(e - m_w) in place
                s += v;
            }
            s += __shfl_xor(s, 1);
            s += __shfl_xor(s, 2);
            s += __shfl_xor(s, 4);
            s += __shfl_xor(s, 8);
            const int rr = i * 16 + g * 4 + rg;
            if (lm == 0) { red[rr][wv][0] = m; red[rr][wv][1] = s; }
            fac[i][rg] = m;  // stash per-wave max
        }
    }
    __syncthreads();
    #pragma unroll
    for (int i = 0; i < 4; ++i) {
        #pragma unroll
        for (int rg = 0; rg < 4; ++rg) {
            const int rr = i * 16 + g * 4 + rg;
            const float m0 = red[rr][0][0], s0 = red[rr][0][1];
            const float m1 = red[rr][1][0], s1 = red[rr][1][1];
            const float m2 = red[rr][2][0], s2 = red[rr][2][1];
            const float m3 = red[rr][3][0], s3 = red[rr][3][1];
            const float M  = fmaxf(fmaxf(m0, m1), fmaxf(m2, m3));
            const float S  = s0 * __expf(m0 - M) + s1 * __expf(m1 - M)
                           + s2 * __expf(m2 - M) + s3 * __expf(m3 - M);
            // P = exp(e - m_w) * exp(m_w - M) / S
            fac[i][rg] = __expf(fac[i][rg] - M) / S;
        }
    }
    #pragma unroll
    for (int i = 0; i < 4; ++i) {
        #pragma unroll
        for (int rg = 0; rg < 4; ++rg) {
            const size_t rr = (size_t)(rowB + i * 16 + g * 4 + rg);
            bf16* p = attn + rr * MEMN + wv * 128 + lm;
            const float f = fac[i][rg];
            #pragma unroll
            for (int j = 0; j < 8; ++j)
                p[j * 16] = (bf16)(acc[i][j][rg] * f);
        }
    }
}

// ---------------- m97-style GEMM: C[M,N] = A[M,K] * Bt[N,K]^T --------------
// 128x128 block tile, BK=32, 256 threads (4 waves, 2x2), 16x16x32 bf16 MFMA.
template <bool OUT_BF16>
__global__ __launch_bounds__(256) void gemm_bt_kernel(const bf16* __restrict__ A,
                                                      const bf16* __restrict__ Bt,
                                                      void* __restrict__ Cv,
                                                      int M, int N, int K) {
    __shared__ bf16 As[128 * 32];
    __shared__ bf16 Bs[128 * 32];

    const int tid  = threadIdx.x;
    const int wave = tid >> 6, lane = tid & 63;
    const int rowB = blockIdx.y * 128;
    const int colB = blockIdx.x * 128;
    const int wrow = (wave >> 1) * 64;
    const int wcol = (wave & 1) * 64;
    const int lm   = lane & 15;
    const int lkb  = (lane >> 4) * 8;

    const int srow  = tid >> 2;
    const int skcol = (tid & 3) * 8;

    const bf16* Ab = A  + (size_t)rowB * K;
    const bf16* Bb = Bt + (size_t)colB * K;

    f32x4 acc[4][4] = {};

    for (int k0 = 0; k0 < K; k0 += 32) {
        __syncthreads();
        gload_lds16(Ab + (size_t)srow * K + k0 + skcol,        As + wave * 512);
        gload_lds16(Ab + (size_t)(srow + 64) * K + k0 + skcol, As + 2048 + wave * 512);
        gload_lds16(Bb + (size_t)srow * K + k0 + skcol,        Bs + wave * 512);
        gload_lds16(Bb + (size_t)(srow + 64) * K + k0 + skcol, Bs + 2048 + wave * 512);
        __syncthreads();

        bf16x8 af[4], bfr[4];
        #pragma unroll
        for (int i = 0; i < 4; ++i)
            af[i] = *(const bf16x8*)(As + (wrow + i * 16 + lm) * 32 + lkb);
        #pragma unroll
        for (int j = 0; j < 4; ++j)
            bfr[j] = *(const bf16x8*)(Bs + (wcol + j * 16 + lm) * 32 + lkb);

        #pragma unroll
        for (int i = 0; i < 4; ++i)
            #pragma unroll
            for (int j = 0; j < 4; ++j)
                acc[i][j] = __builtin_amdgcn_mfma_f32_16x16x32_bf16(
                    af[i], bfr[j], acc[i][j], 0, 0, 0);
    }

    const int r0 = rowB + wrow + (lane >> 4) * 4;
    const int c0 = colB + wcol + lm;
    #pragma unroll
    for (int i = 0; i < 4; ++i) {
        #pragma unroll
        for (int j = 0; j < 4; ++j) {
            #pragma unroll
            for (int r = 0; r < 4; ++r) {
                const size_t off = (size_t)(r0 + i * 16 + r) * N + (c0 + j * 16);
                if (OUT_BF16) ((bf16*)Cv)[off]  = (bf16)acc[i][j][r];
                else          ((float*)Cv)[off] = acc[i][j][r];
            }
        }
    }
}

// ---------------------------------------------------------------------------
extern "C" void kernel_launch(void* const* d_in, const int* in_sizes, int n_in,
                              void* d_out, int out_size, void* d_ws, size_t ws_size,
                              hipStream_t stream) {
    const float* x  = (const float*)d_in[0];
    const float* kr = (const float*)d_in[1];
    const float* ki = (const float*)d_in[2];
    const float* vr = (const float*)d_in[3];
    const float* vi = (const float*)d_in[4];
    float* out = (float*)d_out;

    char* ws = (char*)d_ws;
    bf16* Kb   = (bf16*)ws;                        // 512*1024*2  =  1 MiB
    bf16* VbT  = (bf16*)(ws + 1048576);            // 1024*512*2  =  1 MiB
    bf16* attn = (bf16*)(ws + 2097152);            // 32768*512*2 = 32 MiB

    // 1) pack K' and V'^T (bf16)
    pack_kv_kernel<<<2048, 256, 0, stream>>>(kr, ki, vr, vi, Kb, VbT);
    // 2) fused: energy GEMM (x fp32 read direct) + softmax -> attn bf16
    energy_softmax_kernel<<<512, 256, 0, stream>>>(x, Kb, attn);
    // 3) out = attn @ VbT^T -> fp32 [32768, 1024]
    gemm_bt_kernel<false><<<dim3(8, 256), 256, 0, stream>>>(attn, VbT, out,
                                                            NROWS, DIMX, MEMN);
}

// Round 2
// 317.787 us; speedup vs baseline: 1.1380x; 1.0471x over previous
//
#include <hip/hip_runtime.h>

// ---------------------------------------------------------------------------
// HolographicMemory: out = softmax( x @ [Kr|Ki]^T * temp ) @ [Vr|Vi]
//   x: [32768, 1024] fp32, MEM=512, HEAD=512.
// v3: counted-vmcnt pipelines (T3-min recipe, raw s_barrier + asm waits).
//   energy: X reg-staged (fp32->bf16 cvt at stage time), 2-step-deep X regs,
//           K double-buffered via global_load_lds; end-of-step vmcnt(2).
//   gemm2:  3-deep LDS buffers, steady-state vmcnt(4); XCD-aware block swizzle.
// ---------------------------------------------------------------------------

#define DIMX   1024
#define MEMN   512
#define NROWS  32768
#define TEMP   0.04419417382415922f  // 512^-0.5

typedef __bf16 bf16;
typedef __bf16 bf16x8 __attribute__((ext_vector_type(8)));
typedef float  f32x4  __attribute__((ext_vector_type(4)));

// async global->LDS, 16B per lane; LDS dest is wave-uniform base + lane*16
__device__ __forceinline__ void gload_lds16(const void* g, void* l) {
    __builtin_amdgcn_global_load_lds(
        (const __attribute__((address_space(1))) unsigned*)g,
        (__attribute__((address_space(3))) unsigned*)l,
        16, 0, 0);
}

// counted waitcnt + barrier (loads for future tiles stay in flight)
#define WAITBAR(VM) asm volatile("s_waitcnt vmcnt(" #VM ") lgkmcnt(0)\n\ts_barrier" ::: "memory")

// ------- pack K' = [Kr|Ki] as [512][1024]; V'^T as [1024][512] (bf16) ------
__global__ __launch_bounds__(256) void pack_kv_kernel(const float* __restrict__ kr,
                                                      const float* __restrict__ ki,
                                                      const float* __restrict__ vr,
                                                      const float* __restrict__ vi,
                                                      bf16* __restrict__ Kb,
                                                      bf16* __restrict__ VbT) {
    const int idx = blockIdx.x * 256 + threadIdx.x;   // 0 .. 512*1024-1
    {   // Kb[m][h'] : h'<512 -> Kr[m][h'], else Ki[m][h'-512]
        const int m = idx >> 10, h = idx & 1023;
        const float v = (h < 512) ? kr[m * 512 + h] : ki[m * 512 + (h - 512)];
        Kb[idx] = (bf16)v;
    }
    {   // VbT[h'][m] : h'<512 -> Vr[m][h'], else Vi[m][h'-512]
        const int hp = idx >> 9, m = idx & 511;
        const float v = (hp < 512) ? vr[m * 512 + hp] : vi[m * 512 + (hp - 512)];
        VbT[idx] = (bf16)v;
    }
}

// ---------------------------------------------------------------------------
// Fused energy + softmax. Block: 64 rows x 512 cols (full softmax row),
// 4 waves, wave wv owns cols wv*128..+127 -> acc[4][8] f32x4.
// LDS: Xs 2x[64][32] bf16 (8K), Ks 2x[512][32] bf16 (64K), red 2K = 74K.
// Per-step: stage K(t+1) (8 gload_lds) + issue X(t+2)->regs; compute t;
// cvt+ds_write X(t+1); WAITBAR(2) -- X(t+2)'s 2 loads stay in flight.
// ---------------------------------------------------------------------------
__global__ __launch_bounds__(256, 2) void energy_softmax_kernel(
        const float* __restrict__ x,    // [32768][1024] fp32
        const bf16*  __restrict__ Kb,   // [512][1024]  bf16
        bf16* __restrict__ attn) {      // [32768][512] bf16 out
    __shared__ __align__(16) bf16 Xs[2][64 * 32];
    __shared__ __align__(16) bf16 Ks[2][512 * 32];
    __shared__ float red[64][4][2];     // [row][wave][{max,sum}]

    const int tid  = threadIdx.x;
    const int wv   = tid >> 6, lane = tid & 63;
    const int lm   = lane & 15, g = lane >> 4;   // fragment coords
    const int rowB = blockIdx.x * 64;

    // staging geometry: thread covers row sr = tid>>2, 16B chunk sc = tid&3
    const int sr = tid >> 2;
    const int sc = tid & 3;
    const float* xsrc = x + (size_t)(rowB + sr) * DIMX + sc * 8;
    const int xw_off = sr * 64 + ((sc ^ ((sr >> 1) & 3)) << 4);   // bytes

    f32x4 acc[4][8] = {};
    f32x4 xa0, xb0, xa1, xb1;

#define K_STAGE(B, K0)                                                          \
    _Pragma("unroll")                                                           \
    for (int li = 0; li < 8; ++li) {                                            \
        const int r = li * 64 + sr;                                             \
        gload_lds16(Kb + (size_t)r * DIMX + (K0) + ((sc ^ ((r >> 1) & 3)) << 3),\
                    (char*)Ks[B] + li * 4096 + wv * 1024);                      \
    }

#define X_ISSUE(A, Bv, K0) { A = *(const f32x4*)(xsrc + (K0));                  \
                             Bv = *(const f32x4*)(xsrc + (K0) + 4); }

#define X_WRITE(B, A, Bv) { bf16x8 w;                                           \
    w[0] = (bf16)A[0];  w[1] = (bf16)A[1];  w[2] = (bf16)A[2];  w[3] = (bf16)A[3]; \
    w[4] = (bf16)Bv[0]; w[5] = (bf16)Bv[1]; w[6] = (bf16)Bv[2]; w[7] = (bf16)Bv[3]; \
    *(bf16x8*)((char*)Xs[B] + xw_off) = w; }

#define COMPUTE(B) {                                                            \
    bf16x8 af[4], bfr[8];                                                       \
    _Pragma("unroll") for (int i = 0; i < 4; ++i) {                             \
        const int r = i * 16 + lm;                                              \
        af[i] = *(const bf16x8*)((const char*)Xs[B] + r * 64                    \
                                 + ((g ^ ((r >> 1) & 3)) << 4));                \
    }                                                                           \
    _Pragma("unroll") for (int j = 0; j < 8; ++j) {                             \
        const int r = wv * 128 + j * 16 + lm;                                   \
        bfr[j] = *(const bf16x8*)((const char*)Ks[B] + r * 64                   \
                                  + ((g ^ ((r >> 1) & 3)) << 4));               \
    }                                                                           \
    _Pragma("unroll") for (int i = 0; i < 4; ++i)                               \
        _Pragma("unroll") for (int j = 0; j < 8; ++j)                           \
            acc[i][j] = __builtin_amdgcn_mfma_f32_16x16x32_bf16(                \
                af[i], bfr[j], acc[i][j], 0, 0, 0); }

    // ---- prologue: buf0 = step0; X1 in flight --------------------------------
    K_STAGE(0, 0);
    X_ISSUE(xa0, xb0, 0);
    X_ISSUE(xa1, xb1, 32);
    X_WRITE(0, xa0, xb0);          // compiler inserts exact vmcnt for X0
    WAITBAR(2);                    // K0 landed; X1's 2 loads remain in flight

    // ---- steady state: steps 0..29 (unroll-by-2 for reg/buffer parity) ------
    for (int t = 0; t < 30; t += 2) {
        // even step t (cur = 0)
        K_STAGE(1, (t + 1) * 32);
        X_ISSUE(xa0, xb0, (t + 2) * 32);
        COMPUTE(0);
        X_WRITE(1, xa1, xb1);      // X(t+1); compiler waits its 2 loads
        WAITBAR(2);                // K(t+1) landed; X(t+2) stays in flight
        // odd step t+1 (cur = 1)
        K_STAGE(0, (t + 2) * 32);
        X_ISSUE(xa1, xb1, (t + 3) * 32);
        COMPUTE(1);
        X_WRITE(0, xa0, xb0);      // X(t+2)
        WAITBAR(2);
    }
    // ---- step 30 (cur = 0): stage K31, no new X ------------------------------
    K_STAGE(1, 31 * 32);
    COMPUTE(0);
    X_WRITE(1, xa1, xb1);          // X31
    WAITBAR(0);                    // full drain: K31 landed
    // ---- step 31 (cur = 1) ---------------------------------------------------
    COMPUTE(1);

#undef K_STAGE
#undef X_ISSUE
#undef X_WRITE
#undef COMPUTE

    // ---- softmax epilogue ----------------------------------------------------
    // C/D layout: col = j*16 + lm (+wv*128), row = i*16 + g*4 + reg.
    float fac[4][4];
    #pragma unroll
    for (int i = 0; i < 4; ++i) {
        #pragma unroll
        for (int rg = 0; rg < 4; ++rg) {
            float m = acc[i][0][rg] * TEMP;
            #pragma unroll
            for (int j = 1; j < 8; ++j) m = fmaxf(m, acc[i][j][rg] * TEMP);
            m = fmaxf(m, __shfl_xor(m, 1));
            m = fmaxf(m, __shfl_xor(m, 2));
            m = fmaxf(m, __shfl_xor(m, 4));
            m = fmaxf(m, __shfl_xor(m, 8));
            float s = 0.f;
            #pragma unroll
            for (int j = 0; j < 8; ++j) {
                const float v = __expf(acc[i][j][rg] * TEMP - m);
                acc[i][j][rg] = v;
                s += v;
            }
            s += __shfl_xor(s, 1);
            s += __shfl_xor(s, 2);
            s += __shfl_xor(s, 4);
            s += __shfl_xor(s, 8);
            const int rr = i * 16 + g * 4 + rg;
            if (lm == 0) { red[rr][wv][0] = m; red[rr][wv][1] = s; }
            fac[i][rg] = m;
        }
    }
    __syncthreads();
    #pragma unroll
    for (int i = 0; i < 4; ++i) {
        #pragma unroll
        for (int rg = 0; rg < 4; ++rg) {
            const int rr = i * 16 + g * 4 + rg;
            const float m0 = red[rr][0][0], s0 = red[rr][0][1];
            const float m1 = red[rr][1][0], s1 = red[rr][1][1];
            const float m2 = red[rr][2][0], s2 = red[rr][2][1];
            const float m3 = red[rr][3][0], s3 = red[rr][3][1];
            const float M  = fmaxf(fmaxf(m0, m1), fmaxf(m2, m3));
            const float S  = s0 * __expf(m0 - M) + s1 * __expf(m1 - M)
                           + s2 * __expf(m2 - M) + s3 * __expf(m3 - M);
            fac[i][rg] = __expf(fac[i][rg] - M) / S;
        }
    }
    #pragma unroll
    for (int i = 0; i < 4; ++i) {
        #pragma unroll
        for (int rg = 0; rg < 4; ++rg) {
            const size_t rr = (size_t)(rowB + i * 16 + g * 4 + rg);
            bf16* p = attn + rr * MEMN + wv * 128 + lm;
            const float f = fac[i][rg];
            #pragma unroll
            for (int j = 0; j < 8; ++j)
                p[j * 16] = (bf16)(acc[i][j][rg] * f);
        }
    }
}

// ---------------- pipelined GEMM: C[M,N] = A[M,K] * Bt[N,K]^T --------------
// 128x128 tile, BK=32, 256 threads (4 waves 2x2), 3-deep LDS pipeline with
// counted vmcnt(4); XCD-aware 1-D block swizzle (grid must be %8 == 0).
template <bool OUT_BF16>
__global__ __launch_bounds__(256, 2) void gemm_bt_kernel(const bf16* __restrict__ A,
                                                         const bf16* __restrict__ Bt,
                                                         void* __restrict__ Cv,
                                                         int M, int N, int K) {
    __shared__ bf16 As[3][128 * 32];
    __shared__ bf16 Bs[3][128 * 32];

    // XCD swizzle: hw XCD = blockIdx.x % 8; give each XCD a contiguous chunk
    const int cpx = gridDim.x >> 3;
    const int l   = (blockIdx.x & 7) * cpx + (blockIdx.x >> 3);
    const int nbx = N >> 7;                 // col-blocks (pow2)
    const int bx  = l & (nbx - 1), by = l / nbx;

    const int tid  = threadIdx.x;
    const int wave = tid >> 6, lane = tid & 63;
    const int rowB = by * 128;
    const int colB = bx * 128;
    const int wrow = (wave >> 1) * 64;
    const int wcol = (wave & 1) * 64;
    const int lm   = lane & 15;
    const int lkb  = (lane >> 4) * 8;

    const int srow  = tid >> 2;
    const int skcol = (tid & 3) * 8;

    const bf16* Ab = A  + (size_t)rowB * K;
    const bf16* Bb = Bt + (size_t)colB * K;

    f32x4 acc[4][4] = {};

#define STAGE(B, K0) {                                                          \
    gload_lds16(Ab + (size_t)srow * K + (K0) + skcol,        As[B] + wave * 512); \
    gload_lds16(Ab + (size_t)(srow + 64) * K + (K0) + skcol, As[B] + 2048 + wave * 512); \
    gload_lds16(Bb + (size_t)srow * K + (K0) + skcol,        Bs[B] + wave * 512); \
    gload_lds16(Bb + (size_t)(srow + 64) * K + (K0) + skcol, Bs[B] + 2048 + wave * 512); }

#define G2_COMPUTE(B) {                                                         \
    bf16x8 af[4], bfr[4];                                                       \
    _Pragma("unroll") for (int i = 0; i < 4; ++i)                               \
        af[i] = *(const bf16x8*)(As[B] + (wrow + i * 16 + lm) * 32 + lkb);      \
    _Pragma("unroll") for (int j = 0; j < 4; ++j)                               \
        bfr[j] = *(const bf16x8*)(Bs[B] + (wcol + j * 16 + lm) * 32 + lkb);     \
    _Pragma("unroll") for (int i = 0; i < 4; ++i)                               \
        _Pragma("unroll") for (int j = 0; j < 4; ++j)                           \
            acc[i][j] = __builtin_amdgcn_mfma_f32_16x16x32_bf16(                \
                af[i], bfr[j], acc[i][j], 0, 0, 0); }

    // prologue: stage steps 0,1; wait step0 only (step1's 4 stay in flight)
    STAGE(0, 0);
    STAGE(1, 32);
    WAITBAR(4);
    // steady state: 16 steps total, 3-deep rotation (steps 0..11 in loop)
    for (int t = 0; t < 12; t += 3) {
        STAGE(2, (t + 2) * 32); G2_COMPUTE(0); WAITBAR(4);
        STAGE(0, (t + 3) * 32); G2_COMPUTE(1); WAITBAR(4);
        STAGE(1, (t + 4) * 32); G2_COMPUTE(2); WAITBAR(4);
    }
    // tail: steps 12..15
    STAGE(2, 14 * 32); G2_COMPUTE(0); WAITBAR(4);   // step 12
    STAGE(0, 15 * 32); G2_COMPUTE(1); WAITBAR(4);   // step 13
    G2_COMPUTE(2);                   WAITBAR(0);    // step 14; drain step15
    G2_COMPUTE(0);                                  // step 15

#undef STAGE
#undef G2_COMPUTE

    const int r0 = rowB + wrow + (lane >> 4) * 4;
    const int c0 = colB + wcol + lm;
    #pragma unroll
    for (int i = 0; i < 4; ++i) {
        #pragma unroll
        for (int j = 0; j < 4; ++j) {
            #pragma unroll
            for (int r = 0; r < 4; ++r) {
                const size_t off = (size_t)(r0 + i * 16 + r) * N + (c0 + j * 16);
                if (OUT_BF16) ((bf16*)Cv)[off]  = (bf16)acc[i][j][r];
                else          ((float*)Cv)[off] = acc[i][j][r];
            }
        }
    }
}

// ---------------------------------------------------------------------------
extern "C" void kernel_launch(void* const* d_in, const int* in_sizes, int n_in,
                              void* d_out, int out_size, void* d_ws, size_t ws_size,
                              hipStream_t stream) {
    const float* x  = (const float*)d_in[0];
    const float* kr = (const float*)d_in[1];
    const float* ki = (const float*)d_in[2];
    const float* vr = (const float*)d_in[3];
    const float* vi = (const float*)d_in[4];
    float* out = (float*)d_out;

    char* ws = (char*)d_ws;
    bf16* Kb   = (bf16*)ws;                        // 512*1024*2  =  1 MiB
    bf16* VbT  = (bf16*)(ws + 1048576);            // 1024*512*2  =  1 MiB
    bf16* attn = (bf16*)(ws + 2097152);            // 32768*512*2 = 32 MiB

    // 1) pack K' and V'^T (bf16)
    pack_kv_kernel<<<2048, 256, 0, stream>>>(kr, ki, vr, vi, Kb, VbT);
    // 2) fused: energy GEMM (x fp32, reg-staged) + softmax -> attn bf16
    energy_softmax_kernel<<<512, 256, 0, stream>>>(x, Kb, attn);
    // 3) out = attn @ VbT^T -> fp32 [32768, 1024] (1-D grid, %8==0)
    gemm_bt_kernel<false><<<2048, 256, 0, stream>>>(attn, VbT, out,
                                                    NROWS, DIMX, MEMN);
}

// Round 3
// 292.829 us; speedup vs baseline: 1.2349x; 1.0852x over previous
//
#include <hip/hip_runtime.h>

// ---------------------------------------------------------------------------
// HolographicMemory: out = softmax( x @ [Kr|Ki]^T * temp ) @ [Vr|Vi]
// v4: K/B operands pre-packed in MFMA-fragment order -> loaded straight from
//     L2 into registers (no LDS staging, no ds_read, no K-barriers).
//   energy: per-wave bfr[8] reg double-buffer, 1-step-ahead prefetch; only
//           the 4KB X buffer needs a barrier. LDS 10KB.
//   gemm2:  B-direct same way; A (attn) via global_load_lds double-buffer.
//           LDS 16KB -> 3 blocks/CU for cross-block latency hiding.
// ---------------------------------------------------------------------------

#define DIMX   1024
#define MEMN   512
#define NROWS  32768
#define TEMP   0.04419417382415922f  // 512^-0.5

typedef __bf16 bf16;
typedef __bf16 bf16x8 __attribute__((ext_vector_type(8)));
typedef float  f32x4  __attribute__((ext_vector_type(4)));

// async global->LDS, 16B per lane; LDS dest is wave-uniform base + lane*16
__device__ __forceinline__ void gload_lds16(const void* g, void* l) {
    __builtin_amdgcn_global_load_lds(
        (const __attribute__((address_space(1))) unsigned*)g,
        (__attribute__((address_space(3))) unsigned*)l,
        16, 0, 0);
}
// asm global loads with pinned issue point (prefetch into regs)
__device__ __forceinline__ void gl_b16x8(bf16x8& d, const bf16* p) {
    asm volatile("global_load_dwordx4 %0, %1, off" : "=v"(d) : "v"(p));
}
__device__ __forceinline__ void gl_f32x4(f32x4& d, const float* p) {
    asm volatile("global_load_dwordx4 %0, %1, off" : "=v"(d) : "v"(p));
}
// counted waits; sched_barrier stops MFMA/VALU hoisting above the wait (r18)
#define VMW(N)     do { asm volatile("s_waitcnt vmcnt(" #N ")" ::: "memory"); \
                        __builtin_amdgcn_sched_barrier(0); } while (0)
#define WAITBAR(N) do { asm volatile("s_waitcnt vmcnt(" #N ") lgkmcnt(0)\n\t" \
                        "s_barrier" ::: "memory");                            \
                        __builtin_amdgcn_sched_barrier(0); } while (0)

// ---- pack K' and V'^T in MFMA-fragment order ------------------------------
// Kb_f[c][t][l][e]: c=k-chunk(32), t=row-tile(32), l=g*16+lm, e=0..7
//   element (row=t*16+lm, k=c*32+g*8+e) of K'=[Kr|Ki]  ([512][1024])
// Vb_f[c][t][l][e]: c=k-chunk(16), t=ncol-tile(64)
//   element (n=t*16+lm, k=c*32+g*8+e) of V'^T ([1024][512])
__global__ __launch_bounds__(256) void pack_kv_kernel(const float* __restrict__ kr,
                                                      const float* __restrict__ ki,
                                                      const float* __restrict__ vr,
                                                      const float* __restrict__ vi,
                                                      bf16* __restrict__ Kb,
                                                      bf16* __restrict__ Vb) {
    const int idx = blockIdx.x * 256 + threadIdx.x;   // 0 .. 2^19-1
    const int e = idx & 7, l = (idx >> 3) & 63;
    const int lm = l & 15, g = l >> 4;
    {   // Kb_f
        const int t = (idx >> 9) & 31, c = idx >> 14;
        const int row = t * 16 + lm, k = c * 32 + g * 8 + e;
        const float v = (k < 512) ? kr[row * 512 + k] : ki[row * 512 + (k - 512)];
        Kb[idx] = (bf16)v;
    }
    {   // Vb_f
        const int t = (idx >> 9) & 63, c = idx >> 15;
        const int h = t * 16 + lm, m = c * 32 + g * 8 + e;
        const float v = (h < 512) ? vr[m * 512 + h] : vi[m * 512 + (h - 512)];
        Vb[idx] = (bf16)v;
    }
}

// ---------------------------------------------------------------------------
// Fused energy + softmax. Block: 64 rows x 512 cols, 4 waves; wave wv owns
// cols wv*128..+127 -> acc[4][8]. K direct-from-L2 (fragment order); X
// reg-staged fp32->bf16 into 2x4KB LDS. One barrier per k-step.
// ---------------------------------------------------------------------------
__global__ __launch_bounds__(256, 2) void energy_softmax_kernel(
        const float* __restrict__ x,    // [32768][1024] fp32
        const bf16*  __restrict__ Kb,   // fragment-order, 1 MiB
        bf16* __restrict__ attn) {      // [32768][512] bf16 out
    __shared__ __align__(16) bf16 Xs[2][64 * 32];
    __shared__ float red[64][4][2];     // [row][wave][{max,sum}]

    const int tid  = threadIdx.x;
    const int wv   = tid >> 6, lane = tid & 63;
    const int lm   = lane & 15, g = lane >> 4;
    const int rowB = blockIdx.x * 64;

    // X staging: thread -> row sr, 16B chunk sc
    const int sr = tid >> 2, sc = tid & 3;
    const float* xsrc = x + (size_t)(rowB + sr) * DIMX + sc * 8;
    const int xw_off = sr * 64 + ((sc ^ ((sr >> 1) & 3)) << 4);   // bytes

    // K fragments: wave's col-tiles are Kb row-tiles wv*8+j
    const bf16* kbase = Kb + (wv * 8) * 512 + lane * 8;

    f32x4 acc[4][8] = {};
    f32x4 xa, xb;
    bf16x8 bA[8], bB[8];

#define K_PREF(DST, C) { _Pragma("unroll") for (int j = 0; j < 8; ++j)         \
        gl_b16x8(DST[j], kbase + (size_t)(C) * 16384 + j * 512); }
#define X_PREF(S) { gl_f32x4(xa, xsrc + (S) * 32);                             \
                    gl_f32x4(xb, xsrc + (S) * 32 + 4); }
#define X_WR(B) { bf16x8 w;                                                    \
    w[0]=(bf16)xa[0]; w[1]=(bf16)xa[1]; w[2]=(bf16)xa[2]; w[3]=(bf16)xa[3];    \
    w[4]=(bf16)xb[0]; w[5]=(bf16)xb[1]; w[6]=(bf16)xb[2]; w[7]=(bf16)xb[3];    \
    *(bf16x8*)((char*)Xs[B] + xw_off) = w; }
#define COMPUTE_E(XB, BF) { bf16x8 af[4];                                      \
    _Pragma("unroll") for (int i = 0; i < 4; ++i) { const int r = i * 16 + lm; \
        af[i] = *(const bf16x8*)((const char*)Xs[XB] + r * 64                  \
                                 + ((g ^ ((r >> 1) & 3)) << 4)); }             \
    _Pragma("unroll") for (int i = 0; i < 4; ++i)                              \
        _Pragma("unroll") for (int j = 0; j < 8; ++j)                          \
            acc[i][j] = __builtin_amdgcn_mfma_f32_16x16x32_bf16(               \
                af[i], BF[j], acc[i][j], 0, 0, 0); }

    // prologue: X(0) first (so VMW(8) retires it), then K(0)
    X_PREF(0);                 // [2 in flight]
    K_PREF(bA, 0);             // [10]
    VMW(8);  X_WR(0);          // X(0) ready -> Xs[0]
    X_PREF(1);                 // [10]
    WAITBAR(2);                // K(0) done; X(1) stays in flight

    for (int t = 0; t < 30; t += 2) {
        // step t (even): compute Xs[0] w/ bA
        K_PREF(bB, t + 1);     // [X(t+1)2 + 8]
        COMPUTE_E(0, bA);
        VMW(8);  X_WR(1);      // X(t+1) -> Xs[1]
        X_PREF(t + 2);         // [10]
        WAITBAR(2);            // K(t+1) done
        // step t+1 (odd): compute Xs[1] w/ bB
        K_PREF(bA, t + 2);
        COMPUTE_E(1, bB);
        VMW(8);  X_WR(0);      // X(t+2) -> Xs[0]
        X_PREF(t + 3);
        WAITBAR(2);
    }
    // step 30: compute Xs[0] w/ bA (K30); stage X(31); prefetch K31
    K_PREF(bB, 31);
    COMPUTE_E(0, bA);
    VMW(8);  X_WR(1);          // X(31) -> Xs[1]
    WAITBAR(0);                // K(31) done; nothing in flight
    // step 31
    COMPUTE_E(1, bB);

#undef K_PREF
#undef X_PREF
#undef X_WR
#undef COMPUTE_E

    // ---- softmax epilogue ---------------------------------------------------
    // C/D layout: col = j*16 + lm (+wv*128), row = i*16 + g*4 + reg.
    float fac[4][4];
    #pragma unroll
    for (int i = 0; i < 4; ++i) {
        #pragma unroll
        for (int rg = 0; rg < 4; ++rg) {
            float m = acc[i][0][rg] * TEMP;
            #pragma unroll
            for (int j = 1; j < 8; ++j) m = fmaxf(m, acc[i][j][rg] * TEMP);
            m = fmaxf(m, __shfl_xor(m, 1));
            m = fmaxf(m, __shfl_xor(m, 2));
            m = fmaxf(m, __shfl_xor(m, 4));
            m = fmaxf(m, __shfl_xor(m, 8));
            float s = 0.f;
            #pragma unroll
            for (int j = 0; j < 8; ++j) {
                const float v = __expf(acc[i][j][rg] * TEMP - m);
                acc[i][j][rg] = v;
                s += v;
            }
            s += __shfl_xor(s, 1);
            s += __shfl_xor(s, 2);
            s += __shfl_xor(s, 4);
            s += __shfl_xor(s, 8);
            const int rr = i * 16 + g * 4 + rg;
            if (lm == 0) { red[rr][wv][0] = m; red[rr][wv][1] = s; }
            fac[i][rg] = m;
        }
    }
    __syncthreads();
    #pragma unroll
    for (int i = 0; i < 4; ++i) {
        #pragma unroll
        for (int rg = 0; rg < 4; ++rg) {
            const int rr = i * 16 + g * 4 + rg;
            const float m0 = red[rr][0][0], s0 = red[rr][0][1];
            const float m1 = red[rr][1][0], s1 = red[rr][1][1];
            const float m2 = red[rr][2][0], s2 = red[rr][2][1];
            const float m3 = red[rr][3][0], s3 = red[rr][3][1];
            const float M  = fmaxf(fmaxf(m0, m1), fmaxf(m2, m3));
            const float S  = s0 * __expf(m0 - M) + s1 * __expf(m1 - M)
                           + s2 * __expf(m2 - M) + s3 * __expf(m3 - M);
            fac[i][rg] = __expf(fac[i][rg] - M) / S;
        }
    }
    #pragma unroll
    for (int i = 0; i < 4; ++i) {
        #pragma unroll
        for (int rg = 0; rg < 4; ++rg) {
            const size_t rr = (size_t)(rowB + i * 16 + g * 4 + rg);
            bf16* p = attn + rr * MEMN + wv * 128 + lm;
            const float f = fac[i][rg];
            #pragma unroll
            for (int j = 0; j < 8; ++j)
                p[j * 16] = (bf16)(acc[i][j][rg] * f);
        }
    }
}

// ---------------------------------------------------------------------------
// gemm2: out[32768,1024] = attn[32768,512] @ V'  (B in fragment order, direct
// from L2 into regs). A staged via global_load_lds, 2x8KB, swizzled source.
// 128x128 tile, 4 waves 2x2, 16 k-steps. 3 blocks/CU. XCD-aware swizzle.
// ---------------------------------------------------------------------------
__global__ __launch_bounds__(256, 3) void gemm2_kernel(const bf16* __restrict__ A,
                                                       const bf16* __restrict__ Vb,
                                                       float* __restrict__ C) {
    __shared__ __align__(16) bf16 As[2][128 * 32];

    // XCD swizzle (grid 2048, %8==0)
    const int cpx = gridDim.x >> 3;
    const int l   = ((int)blockIdx.x & 7) * cpx + ((int)blockIdx.x >> 3);
    const int bx  = l & 7, by = l >> 3;          // N/128 = 8 col-blocks

    const int tid  = threadIdx.x;
    const int wave = tid >> 6, lane = tid & 63;
    const int lm   = lane & 15, g = lane >> 4;
    const int rowB = by * 128;
    const int wrow = (wave >> 1) * 64;

    const bf16* vbase = Vb + (bx * 8 + (wave & 1) * 4) * 512 + lane * 8;

    f32x4 acc[4][4] = {};
    bf16x8 bA[4], bB[4];

#define STAGE_A(B, C0) { _Pragma("unroll") for (int li = 0; li < 2; ++li) {     \
        const int q = wave * 2 + li;                                            \
        const int r = q * 16 + (lane >> 2);                                     \
        const int ch = lane & 3;                                                \
        gload_lds16(A + (size_t)(rowB + r) * 512 + (C0) * 32                    \
                      + ((ch ^ ((r >> 1) & 3)) << 3),                           \
                    (char*)As[B] + q * 1024); } }
#define B_PREF(DST, C0) { _Pragma("unroll") for (int j = 0; j < 4; ++j)         \
        gl_b16x8(DST[j], vbase + (size_t)(C0) * 32768 + j * 512); }
#define COMPUTE_G(XB, BF) { bf16x8 af[4];                                       \
    _Pragma("unroll") for (int i = 0; i < 4; ++i) {                             \
        const int r = wrow + i * 16 + lm;                                       \
        af[i] = *(const bf16x8*)((const char*)As[XB] + r * 64                   \
                                 + ((g ^ ((r >> 1) & 3)) << 4)); }              \
    _Pragma("unroll") for (int i = 0; i < 4; ++i)                               \
        _Pragma("unroll") for (int j = 0; j < 4; ++j)                           \
            acc[i][j] = __builtin_amdgcn_mfma_f32_16x16x32_bf16(                \
                af[i], BF[j], acc[i][j], 0, 0, 0); }

    STAGE_A(0, 0);             // [2]
    B_PREF(bA, 0);             // [6]
    WAITBAR(0);
    for (int t = 0; t < 14; t += 2) {
        STAGE_A(1, t + 1); B_PREF(bB, t + 1); COMPUTE_G(0, bA); WAITBAR(0);
        STAGE_A(0, t + 2); B_PREF(bA, t + 2); COMPUTE_G(1, bB); WAITBAR(0);
    }
    STAGE_A(1, 15); B_PREF(bB, 15); COMPUTE_G(0, bA); WAITBAR(0);
    COMPUTE_G(1, bB);

#undef STAGE_A
#undef B_PREF
#undef COMPUTE_G

    // C/D layout: col = lane&15 (+tiles), row = (lane>>4)*4 + reg
    const int r0 = rowB + wrow + g * 4;
    const int c0 = bx * 128 + (wave & 1) * 64 + lm;
    #pragma unroll
    for (int i = 0; i < 4; ++i) {
        #pragma unroll
        for (int j = 0; j < 4; ++j) {
            #pragma unroll
            for (int r = 0; r < 4; ++r)
                C[(size_t)(r0 + i * 16 + r) * DIMX + (c0 + j * 16)] = acc[i][j][r];
        }
    }
}

// ---------------------------------------------------------------------------
extern "C" void kernel_launch(void* const* d_in, const int* in_sizes, int n_in,
                              void* d_out, int out_size, void* d_ws, size_t ws_size,
                              hipStream_t stream) {
    const float* x  = (const float*)d_in[0];
    const float* kr = (const float*)d_in[1];
    const float* ki = (const float*)d_in[2];
    const float* vr = (const float*)d_in[3];
    const float* vi = (const float*)d_in[4];
    float* out = (float*)d_out;

    char* ws = (char*)d_ws;
    bf16* Kb   = (bf16*)ws;                        // 1 MiB (fragment order)
    bf16* Vb   = (bf16*)(ws + 1048576);            // 1 MiB (fragment order)
    bf16* attn = (bf16*)(ws + 2097152);            // 32 MiB

    pack_kv_kernel<<<2048, 256, 0, stream>>>(kr, ki, vr, vi, Kb, Vb);
    energy_softmax_kernel<<<512, 256, 0, stream>>>(x, Kb, attn);
    gemm2_kernel<<<2048, 256, 0, stream>>>(attn, Vb, out);
}

// Round 4
// 291.496 us; speedup vs baseline: 1.2406x; 1.0046x over previous
//
#include <hip/hip_runtime.h>

// ---------------------------------------------------------------------------
// HolographicMemory: out = softmax( x @ [Kr|Ki]^T * temp ) @ [Vr|Vi]
// v5: TCP-saturation schedule. Same byte counts as v4; waits reordered so
//     every load gets a FULL step of coverage and the end-of-step barrier
//     waits on nothing (vmcnt stays high). setprio(1) around MFMA (T5).
//   energy: pre-compute VMW(10) retires K(t) [full-step coverage]; WAITBAR(10)
//           at step end is barrier-only. K in regs (fragment-order pack).
//   gemm2:  4-buffer A (LDS), 2-deep A-stage, B-regs retired pre-compute,
//           single mid-body barrier. XCD swizzle kept.
// ---------------------------------------------------------------------------

#define DIMX   1024
#define MEMN   512
#define NROWS  32768
#define TEMP   0.04419417382415922f  // 512^-0.5

typedef __bf16 bf16;
typedef __bf16 bf16x8 __attribute__((ext_vector_type(8)));
typedef float  f32x4  __attribute__((ext_vector_type(4)));

__device__ __forceinline__ void gload_lds16(const void* g, void* l) {
    __builtin_amdgcn_global_load_lds(
        (const __attribute__((address_space(1))) unsigned*)g,
        (__attribute__((address_space(3))) unsigned*)l,
        16, 0, 0);
}
__device__ __forceinline__ void gl_b16x8(bf16x8& d, const bf16* p) {
    asm volatile("global_load_dwordx4 %0, %1, off" : "=v"(d) : "v"(p));
}
__device__ __forceinline__ void gl_f32x4(f32x4& d, const float* p) {
    asm volatile("global_load_dwordx4 %0, %1, off" : "=v"(d) : "v"(p));
}
// counted waits; sched_barrier stops reg-only MFMA hoisting past the wait (r18)
#define VMW(N)     do { asm volatile("s_waitcnt vmcnt(" #N ")" ::: "memory"); \
                        __builtin_amdgcn_sched_barrier(0); } while (0)
#define WAITBAR(N) do { asm volatile("s_waitcnt vmcnt(" #N ") lgkmcnt(0)\n\t" \
                        "s_barrier" ::: "memory");                            \
                        __builtin_amdgcn_sched_barrier(0); } while (0)
#define VMWBAR(N)  do { asm volatile("s_waitcnt vmcnt(" #N ")\n\t"            \
                        "s_barrier" ::: "memory");                            \
                        __builtin_amdgcn_sched_barrier(0); } while (0)

// ---- pack K' and V'^T in MFMA-fragment order ------------------------------
// Kb_f[c][t][l][e]: element (row=t*16+lm, k=c*32+g*8+e) of K'=[Kr|Ki]
// Vb_f[c][t][l][e]: element (n=t*16+lm, k=c*32+g*8+e) of V'^T [1024][512]
__global__ __launch_bounds__(256) void pack_kv_kernel(const float* __restrict__ kr,
                                                      const float* __restrict__ ki,
                                                      const float* __restrict__ vr,
                                                      const float* __restrict__ vi,
                                                      bf16* __restrict__ Kb,
                                                      bf16* __restrict__ Vb) {
    const int idx = blockIdx.x * 256 + threadIdx.x;   // 0 .. 2^19-1
    const int e = idx & 7, l = (idx >> 3) & 63;
    const int lm = l & 15, g = l >> 4;
    {   // Kb_f
        const int t = (idx >> 9) & 31, c = idx >> 14;
        const int row = t * 16 + lm, k = c * 32 + g * 8 + e;
        const float v = (k < 512) ? kr[row * 512 + k] : ki[row * 512 + (k - 512)];
        Kb[idx] = (bf16)v;
    }
    {   // Vb_f
        const int t = (idx >> 9) & 63, c = idx >> 15;
        const int h = t * 16 + lm, m = c * 32 + g * 8 + e;
        const float v = (h < 512) ? vr[m * 512 + h] : vi[m * 512 + (h - 512)];
        Vb[idx] = (bf16)v;
    }
}

// ---------------------------------------------------------------------------
// Fused energy + softmax. 64 rows x 512 cols per block, 4 waves (col-split).
// Steady step t:  K_PREF(t+1) | VMW(10) retires K(t) [full-step coverage]
//   | COMPUTE(t) | VMW(8) retires X(t+1) | X_WR | X_PREF(t+2) | WAITBAR(10).
// ---------------------------------------------------------------------------
__global__ __launch_bounds__(256, 2) void energy_softmax_kernel(
        const float* __restrict__ x,    // [32768][1024] fp32
        const bf16*  __restrict__ Kb,   // fragment-order, 1 MiB
        bf16* __restrict__ attn) {      // [32768][512] bf16 out
    __shared__ __align__(16) bf16 Xs[2][64 * 32];
    __shared__ float red[64][4][2];

    const int tid  = threadIdx.x;
    const int wv   = tid >> 6, lane = tid & 63;
    const int lm   = lane & 15, g = lane >> 4;
    const int rowB = blockIdx.x * 64;

    const int sr = tid >> 2, sc = tid & 3;
    const float* xsrc = x + (size_t)(rowB + sr) * DIMX + sc * 8;
    const int xw_off = sr * 64 + ((sc ^ ((sr >> 1) & 3)) << 4);   // bytes

    const bf16* kbase = Kb + (wv * 8) * 512 + lane * 8;

    f32x4 acc[4][8] = {};
    f32x4 xa, xb;
    bf16x8 kf0[8], kf1[8];

#define K_PREF(DST, C) { _Pragma("unroll") for (int j = 0; j < 8; ++j)         \
        gl_b16x8(DST[j], kbase + (size_t)(C) * 16384 + j * 512); }
#define X_PREF(S) { gl_f32x4(xa, xsrc + (S) * 32);                             \
                    gl_f32x4(xb, xsrc + (S) * 32 + 4); }
#define X_WR(B) { bf16x8 w;                                                    \
    w[0]=(bf16)xa[0]; w[1]=(bf16)xa[1]; w[2]=(bf16)xa[2]; w[3]=(bf16)xa[3];    \
    w[4]=(bf16)xb[0]; w[5]=(bf16)xb[1]; w[6]=(bf16)xb[2]; w[7]=(bf16)xb[3];    \
    *(bf16x8*)((char*)Xs[B] + xw_off) = w; }
#define COMPUTE_E(XB, KF) { bf16x8 af[4];                                      \
    _Pragma("unroll") for (int i = 0; i < 4; ++i) { const int r = i * 16 + lm; \
        af[i] = *(const bf16x8*)((const char*)Xs[XB] + r * 64                  \
                                 + ((g ^ ((r >> 1) & 3)) << 4)); }             \
    __builtin_amdgcn_s_setprio(1);                                             \
    _Pragma("unroll") for (int i = 0; i < 4; ++i)                              \
        _Pragma("unroll") for (int j = 0; j < 8; ++j)                          \
            acc[i][j] = __builtin_amdgcn_mfma_f32_16x16x32_bf16(               \
                af[i], KF[j], acc[i][j], 0, 0, 0);                             \
    __builtin_amdgcn_s_setprio(0); }
// one steady-state step: entry queue = [K(t)8, X(t+1)2]
#define STEP_E(KCUR, KNXT, XB, CH_K, CH_X)                                     \
    K_PREF(KNXT, CH_K);            /* -> 18 in flight */                       \
    VMW(10);                       /* retire K(t): full-step coverage */       \
    COMPUTE_E(XB, KCUR);                                                       \
    VMW(8);                        /* retire X(t+1) */                         \
    X_WR((XB) ^ 1);                                                           \
    X_PREF(CH_X);                  /* -> 10 in flight */                       \
    WAITBAR(10);                   /* barrier only: waits nothing */

    // ---- prologue -----------------------------------------------------------
    X_PREF(0);                 // [X0:2]
    K_PREF(kf0, 0);            // [10]
    VMW(8);  X_WR(0);          // X0 -> Xs[0]
    X_PREF(1);                 // [K0:8, X1:2]
    WAITBAR(10);               // barrier only

    // ---- steps 0..29 (unroll 2: kf/Xs parity) -------------------------------
    for (int t = 0; t < 30; t += 2) {
        STEP_E(kf0, kf1, 0, t + 1, t + 2);
        STEP_E(kf1, kf0, 1, t + 2, t + 3);
    }
    // ---- step 30 ------------------------------------------------------------
    K_PREF(kf1, 31);           // [K30:8, X31:2, K31:8]
    VMW(10);                   // retire K30
    COMPUTE_E(0, kf0);
    VMW(8);                    // retire X31
    X_WR(1);
    WAITBAR(8);                // barrier; K31 stays in flight
    // ---- step 31 ------------------------------------------------------------
    VMW(0);                    // retire K31 (full-step coverage)
    COMPUTE_E(1, kf1);

#undef K_PREF
#undef X_PREF
#undef X_WR
#undef COMPUTE_E
#undef STEP_E

    // ---- softmax epilogue ---------------------------------------------------
    // C/D layout: col = j*16 + lm (+wv*128), row = i*16 + g*4 + reg.
    float fac[4][4];
    #pragma unroll
    for (int i = 0; i < 4; ++i) {
        #pragma unroll
        for (int rg = 0; rg < 4; ++rg) {
            float m = acc[i][0][rg] * TEMP;
            #pragma unroll
            for (int j = 1; j < 8; ++j) m = fmaxf(m, acc[i][j][rg] * TEMP);
            m = fmaxf(m, __shfl_xor(m, 1));
            m = fmaxf(m, __shfl_xor(m, 2));
            m = fmaxf(m, __shfl_xor(m, 4));
            m = fmaxf(m, __shfl_xor(m, 8));
            float s = 0.f;
            #pragma unroll
            for (int j = 0; j < 8; ++j) {
                const float v = __expf(acc[i][j][rg] * TEMP - m);
                acc[i][j][rg] = v;
                s += v;
            }
            s += __shfl_xor(s, 1);
            s += __shfl_xor(s, 2);
            s += __shfl_xor(s, 4);
            s += __shfl_xor(s, 8);
            const int rr = i * 16 + g * 4 + rg;
            if (lm == 0) { red[rr][wv][0] = m; red[rr][wv][1] = s; }
            fac[i][rg] = m;
        }
    }
    __syncthreads();
    #pragma unroll
    for (int i = 0; i < 4; ++i) {
        #pragma unroll
        for (int rg = 0; rg < 4; ++rg) {
            const int rr = i * 16 + g * 4 + rg;
            const float m0 = red[rr][0][0], s0 = red[rr][0][1];
            const float m1 = red[rr][1][0], s1 = red[rr][1][1];
            const float m2 = red[rr][2][0], s2 = red[rr][2][1];
            const float m3 = red[rr][3][0], s3 = red[rr][3][1];
            const float M  = fmaxf(fmaxf(m0, m1), fmaxf(m2, m3));
            const float S  = s0 * __expf(m0 - M) + s1 * __expf(m1 - M)
                           + s2 * __expf(m2 - M) + s3 * __expf(m3 - M);
            fac[i][rg] = __expf(fac[i][rg] - M) / S;
        }
    }
    #pragma unroll
    for (int i = 0; i < 4; ++i) {
        #pragma unroll
        for (int rg = 0; rg < 4; ++rg) {
            const size_t rr = (size_t)(rowB + i * 16 + g * 4 + rg);
            bf16* p = attn + rr * MEMN + wv * 128 + lm;
            const float f = fac[i][rg];
            #pragma unroll
            for (int j = 0; j < 8; ++j)
                p[j * 16] = (bf16)(acc[i][j][rg] * f);
        }
    }
}

// ---------------------------------------------------------------------------
// gemm2: out[32768,1024] = attn @ V'. B in fragment order direct-to-regs;
// A via global_load_lds into 4 rotating buffers (2-deep stage). One barrier
// per step (after VMW that retires next A / current B; before compute).
// Buffer safety: stage target (t+2)&3 is never read by waves at t-1 or t.
// ---------------------------------------------------------------------------
__global__ __launch_bounds__(256, 2) void gemm2_kernel(const bf16* __restrict__ A,
                                                       const bf16* __restrict__ Vb,
                                                       float* __restrict__ C) {
    __shared__ __align__(16) bf16 As[4][128 * 32];

    // XCD swizzle (grid 2048, %8==0)
    const int cpx = gridDim.x >> 3;
    const int l   = ((int)blockIdx.x & 7) * cpx + ((int)blockIdx.x >> 3);
    const int bx  = l & 7, by = l >> 3;          // 8 col-blocks

    const int tid  = threadIdx.x;
    const int wave = tid >> 6, lane = tid & 63;
    const int lm   = lane & 15, g = lane >> 4;
    const int rowB = by * 128;
    const int wrow = (wave >> 1) * 64;

    const bf16* vbase = Vb + (bx * 8 + (wave & 1) * 4) * 512 + lane * 8;

    f32x4 acc[4][4] = {};
    bf16x8 bf0[4], bf1[4];

#define A_STAGE(BI, C0) { _Pragma("unroll") for (int li = 0; li < 2; ++li) {    \
        const int q = wave * 2 + li;                                            \
        const int r = q * 16 + (lane >> 2);                                     \
        const int ch = lane & 3;                                                \
        gload_lds16(A + (size_t)(rowB + r) * 512 + (C0) * 32                    \
                      + ((ch ^ ((r >> 1) & 3)) << 3),                           \
                    (char*)As[BI] + q * 1024); } }
#define B_PREF(DST, C0) { _Pragma("unroll") for (int j = 0; j < 4; ++j)         \
        gl_b16x8(DST[j], vbase + (size_t)(C0) * 32768 + j * 512); }
#define COMPUTE_G(BI, BF) { bf16x8 af[4];                                       \
    _Pragma("unroll") for (int i = 0; i < 4; ++i) {                             \
        const int r = wrow + i * 16 + lm;                                       \
        af[i] = *(const bf16x8*)((const char*)As[BI] + r * 64                   \
                                 + ((g ^ ((r >> 1) & 3)) << 4)); }              \
    __builtin_amdgcn_s_setprio(1);                                              \
    _Pragma("unroll") for (int i = 0; i < 4; ++i)                               \
        _Pragma("unroll") for (int j = 0; j < 4; ++j)                           \
            acc[i][j] = __builtin_amdgcn_mfma_f32_16x16x32_bf16(                \
                af[i], BF[j], acc[i][j], 0, 0, 0);                              \
    __builtin_amdgcn_s_setprio(0); }
// steady body t: entry queue = [A(t+1)2, B(t)4]
#define STEP_G(BCUR, BNXT, T)                                                   \
    A_STAGE((T + 2) & 3, T + 2);   /* -> A(t+1),B(t),A(t+2) */                  \
    B_PREF(BNXT, T + 1);           /* -> 12 */                                  \
    VMW(6);                        /* retire A(t+1)+B(t), both full-body */     \
    VMWBAR(6);                     /* barrier: all waves' A(t) long landed */   \
    COMPUTE_G((T) & 3, BCUR);

    // prologue: A0, A1, B0  (queue = 8: A0 2, A1 2, B0 4)
    A_STAGE(0, 0);
    A_STAGE(1, 1);
    B_PREF(bf0, 0);
    // bodies 0..13 (unroll 2 for bf parity); body t stages A(t+2), B(t+1)
    for (int t = 0; t < 14; t += 2) {
        STEP_G(bf0, bf1, t);         // body t   (even): compute bf0
        STEP_G(bf1, bf0, t + 1);     // body t+1 (odd):  compute bf1
    }
    // body 14: stage only B15 (A16 doesn't exist)
    B_PREF(bf1, 15);                 // queue: A15 2, B14 4, B15 4 = 10
    VMW(4);                          // retire A15 + B14
    VMWBAR(4);
    COMPUTE_G(2, bf0);               // buffer 14&3 = 2
    // body 15
    VMW(0);                          // retire B15 (full-body coverage)
    COMPUTE_G(3, bf1);               // buffer 15&3 = 3

#undef A_STAGE
#undef B_PREF
#undef COMPUTE_G
#undef STEP_G

    // C/D layout: col = lane&15 (+tiles), row = (lane>>4)*4 + reg
    const int r0 = rowB + wrow + g * 4;
    const int c0 = bx * 128 + (wave & 1) * 64 + lm;
    #pragma unroll
    for (int i = 0; i < 4; ++i) {
        #pragma unroll
        for (int j = 0; j < 4; ++j) {
            #pragma unroll
            for (int r = 0; r < 4; ++r)
                C[(size_t)(r0 + i * 16 + r) * DIMX + (c0 + j * 16)] = acc[i][j][r];
        }
    }
}

// ---------------------------------------------------------------------------
extern "C" void kernel_launch(void* const* d_in, const int* in_sizes, int n_in,
                              void* d_out, int out_size, void* d_ws, size_t ws_size,
                              hipStream_t stream) {
    const float* x  = (const float*)d_in[0];
    const float* kr = (const float*)d_in[1];
    const float* ki = (const float*)d_in[2];
    const float* vr = (const float*)d_in[3];
    const float* vi = (const float*)d_in[4];
    float* out = (float*)d_out;

    char* ws = (char*)d_ws;
    bf16* Kb   = (bf16*)ws;                        // 1 MiB (fragment order)
    bf16* Vb   = (bf16*)(ws + 1048576);            // 1 MiB (fragment order)
    bf16* attn = (bf16*)(ws + 2097152);            // 32 MiB

    pack_kv_kernel<<<2048, 256, 0, stream>>>(kr, ki, vr, vi, Kb, Vb);
    energy_softmax_kernel<<<512, 256, 0, stream>>>(x, Kb, attn);
    gemm2_kernel<<<2048, 256, 0, stream>>>(attn, Vb, out);
}